// Round 2
// baseline (311.740 us; speedup 1.0000x reference)
//
#include <hip/hip_runtime.h>

#define NN   120000
#define NP   120064   // 938 * 128, padded rows
#define EPSV 1e-5f

typedef __attribute__((ext_vector_type(8))) short          short8v;   // bf16 MFMA frag
typedef __attribute__((ext_vector_type(8))) unsigned short ushort8v;
typedef __attribute__((ext_vector_type(4))) float          f32x4;

__device__ __forceinline__ float b2f(unsigned short u) {
    union { unsigned int i; float f; } x; x.i = ((unsigned int)u) << 16; return x.f;
}
__device__ __forceinline__ unsigned short f2b(float f) {
    union { float f; unsigned int i; } x; x.f = f;
    unsigned int i = x.i + 0x7FFFu + ((x.i >> 16) & 1u);
    return (unsigned short)(i >> 16);
}

// ---------------------------------------------------------------------------
// wprep: convert w2/w3/w4 (f32, [cout][kd] row-major) to bf16 MFMA-fragment
// layout: out[((cb*KBLK + kb)*64 + lane)*8 + e] = bf16(W[cb*16+(lane&15)][kb*32+(lane>>4)*8+e])
// so a wave's B-fragment load is 64 consecutive 16B chunks (fully coalesced).
// W2' at 0 (16384 elems), W3' at 16384 (32768), W4' at 49152 (32768).
// ---------------------------------------------------------------------------
__global__ __launch_bounds__(256) void wprep_kernel(
    const float* __restrict__ w2, const float* __restrict__ w3,
    const float* __restrict__ w4, unsigned short* __restrict__ wb)
{
    int t = blockIdx.x * 256 + threadIdx.x;
    const float* src; int KD, ks; unsigned short* dst; int f;
    if (t < 16384)      { src = w2; KD = 128; ks = 2; dst = wb;         f = t; }
    else if (t < 49152) { src = w3; KD = 128; ks = 2; dst = wb + 16384; f = t - 16384; }
    else                { src = w4; KD = 256; ks = 3; dst = wb + 49152; f = t - 49152; }
    int e = f & 7, l = (f >> 3) & 63;
    int rest = f >> 9;
    int kb = rest & ((1 << ks) - 1);
    int cb = rest >> ks;
    int col = cb * 16 + (l & 15);
    int k = kb * 32 + (l >> 4) * 8 + e;
    dst[f] = f2b(src[col * KD + k]);
}

// ---------------------------------------------------------------------------
// K1: y1 = feat @ w1.T  (K=5), raw output (no BN), accumulate per-channel stats.
// ---------------------------------------------------------------------------
__global__ __launch_bounds__(256) void k1_kernel(
    const float* __restrict__ feat, const float* __restrict__ w1,
    unsigned short* __restrict__ y1, float* __restrict__ stat1)
{
    __shared__ float red[512];
    const int tid = threadIdx.x;
    const int c = tid & 127;
    const int rh = tid >> 7;
    const int rowbase = blockIdx.x * 128;

    float wr_[5];
#pragma unroll
    for (int k = 0; k < 5; ++k) wr_[k] = w1[c * 5 + k];

    float ls = 0.f, lq = 0.f;
#pragma unroll 4
    for (int i = 0; i < 64; ++i) {
        int row = rowbase + i * 2 + rh;
        float y = 0.f;
        if (row < NN) {
            const float* fp = feat + (size_t)row * 5;
            y = fp[0]*wr_[0] + fp[1]*wr_[1] + fp[2]*wr_[2] + fp[3]*wr_[3] + fp[4]*wr_[4];
        }
        y1[(size_t)row * 128 + c] = f2b(y);
        ls += y; lq += y * y;
    }
    red[tid] = ls; red[tid + 256] = lq;
    __syncthreads();
    if (tid < 128) {
        atomicAdd(&stat1[tid],       red[tid]       + red[tid + 128]);
        atomicAdd(&stat1[128 + tid], red[tid + 256] + red[tid + 384]);
    }
}

// ---------------------------------------------------------------------------
// GEMM, fused input-BN+relu, output stats. B fragments straight from global
// (fragment-linear bf16 weights, L2-hot) -> registers; A through 32KB LDS
// with XOR swizzle. 128x128 tile / block, 4 waves (64x64 each).
// ---------------------------------------------------------------------------
template<int KD>
__global__ __launch_bounds__(256) void gemm_bn_kernel(
    const unsigned short* __restrict__ X, const float* __restrict__ statsIn,
    const float* __restrict__ gIn, const float* __restrict__ bIn,
    const unsigned short* __restrict__ Wf, unsigned short* __restrict__ Y,
    float* __restrict__ statsOut, int coutTotal)
{
    constexpr int KBLK = KD / 32;
    __shared__ char lds[32768 + 2 * KD * 4];
    char* As = lds;
    float* scl = (float*)(lds + 32768);
    float* bia = (float*)(lds + 32768 + KD * 4);

    const int tid = threadIdx.x;
    const int rowbase = blockIdx.x * 128;
    const int cbase = blockIdx.y * 128;

    if (tid < KD) {
        float mean = statsIn[tid] * (1.0f / NN);
        float var  = statsIn[KD + tid] * (1.0f / NN) - mean * mean;
        float s    = gIn[tid] * rsqrtf(var + EPSV);
        scl[tid] = s;
        bia[tid] = bIn[tid] - mean * s;
    }
    __syncthreads();

    f32x4 acc[4][4] = {};

    const int l  = tid & 63;
    const int wv = tid >> 6;
    const int wr = wv >> 1, wc = wv & 1;
    const int lm = l & 15, lg = l >> 4;
    const int cb0 = (cbase >> 4) + wc * 4;

#pragma unroll
    for (int kc = 0; kc < KD / 128; ++kc) {
        if (kc) __syncthreads();
        // ---- stage A chunk (BN+relu applied, f32->bf16), coalesced ----
#pragma unroll
        for (int i = 0; i < 8; ++i) {
            int e = i * 256 + tid;           // 0..2047
            int row = e >> 4;                // 0..127
            int k8 = (e & 15) * 8;           // 0..120
            ushort8v v = *(const ushort8v*)(X + (size_t)(rowbase + row) * KD + kc * 128 + k8);
            int kg0 = kc * 128 + k8;
            f32x4 s0 = *(const f32x4*)(scl + kg0);
            f32x4 s1 = *(const f32x4*)(scl + kg0 + 4);
            f32x4 c0 = *(const f32x4*)(bia + kg0);
            f32x4 c1 = *(const f32x4*)(bia + kg0 + 4);
            ushort8v o;
#pragma unroll
            for (int j = 0; j < 4; ++j)
                o[j] = f2b(fmaxf(b2f(v[j]) * s0[j] + c0[j], 0.f));
#pragma unroll
            for (int j = 0; j < 4; ++j)
                o[4 + j] = f2b(fmaxf(b2f(v[4 + j]) * s1[j] + c1[j], 0.f));
            *(ushort8v*)(As + row * 256 + ((k8 * 2) ^ ((row & 7) << 4))) = o;
        }
        __syncthreads();
        // ---- MFMA: A from LDS, B fragments from global (coalesced, L2-hot) ----
#pragma unroll
        for (int kk = 0; kk < 4; ++kk) {
            short8v a[4], b[4];
            int kb2 = (kk * 32 + lg * 8) * 2;
#pragma unroll
            for (int ni = 0; ni < 4; ++ni)
                b[ni] = *(const short8v*)(Wf + ((size_t)((cb0 + ni) * KBLK + kc * 4 + kk) * 64 + l) * 8);
#pragma unroll
            for (int mi = 0; mi < 4; ++mi) {
                int r = wr * 64 + mi * 16 + lm;
                a[mi] = *(const short8v*)(As + r * 256 + (kb2 ^ ((r & 7) << 4)));
            }
#pragma unroll
            for (int mi = 0; mi < 4; ++mi)
#pragma unroll
                for (int ni = 0; ni < 4; ++ni)
                    acc[mi][ni] = __builtin_amdgcn_mfma_f32_16x16x32_bf16(a[mi], b[ni], acc[mi][ni], 0, 0, 0);
        }
    }

    // ---- per-channel stats (masked to real rows) ----
#pragma unroll
    for (int ni = 0; ni < 4; ++ni) {
        float s = 0.f, q = 0.f;
#pragma unroll
        for (int mi = 0; mi < 4; ++mi)
#pragma unroll
            for (int r = 0; r < 4; ++r) {
                int rowg = rowbase + wr * 64 + mi * 16 + lg * 4 + r;
                float v = acc[mi][ni][r];
                v = (rowg < NN) ? v : 0.f;
                s += v; q += v * v;
            }
        s += __shfl_xor(s, 16); s += __shfl_xor(s, 32);
        q += __shfl_xor(q, 16); q += __shfl_xor(q, 32);
        if (lg == 0) {
            int cg = cbase + wc * 64 + ni * 16 + lm;
            atomicAdd(&statsOut[cg], s);
            atomicAdd(&statsOut[coutTotal + cg], q);
        }
    }

    // ---- C -> LDS -> coalesced global store (bf16), reusing As ----
    __syncthreads();
#pragma unroll
    for (int mi = 0; mi < 4; ++mi)
#pragma unroll
        for (int ni = 0; ni < 4; ++ni)
#pragma unroll
            for (int r = 0; r < 4; ++r) {
                int row = wr * 64 + mi * 16 + lg * 4 + r;
                int colb = (wc * 64 + ni * 16 + lm) * 2;
                *(unsigned short*)(As + row * 256 + (colb ^ ((row & 7) << 4))) = f2b(acc[mi][ni][r]);
            }
    __syncthreads();
    {
        int row = tid >> 1;
        int hb = (tid & 1) * 128;   // byte base within row
        unsigned short* Yrow = Y + (size_t)(rowbase + row) * coutTotal + cbase + (hb >> 1);
#pragma unroll
        for (int j = 0; j < 8; ++j) {
            ushort8v v = *(const ushort8v*)(As + row * 256 + ((hb + j * 16) ^ ((row & 7) << 4)));
            *(ushort8v*)(Yrow + j * 8) = v;
        }
    }
}

// ---------------------------------------------------------------------------
// K5: x5 = relu( BN4(y4) + relu(BN2(y2)) ); logits = x5 @ w_out.T + b_out
// ---------------------------------------------------------------------------
__global__ __launch_bounds__(256) void k5_kernel(
    const unsigned short* __restrict__ y2, const unsigned short* __restrict__ y4,
    const float* __restrict__ stat2, const float* __restrict__ g2, const float* __restrict__ b2,
    const float* __restrict__ stat4, const float* __restrict__ g4, const float* __restrict__ b4,
    const float* __restrict__ w_out, const float* __restrict__ b_out,
    float* __restrict__ out)
{
    __shared__ float wT[128 * 8];
    __shared__ float sc2[128], bi2[128], sc4[128], bi4[128], bo[8];
    const int tid = threadIdx.x;

    if (tid < 128) {
        float m2 = stat2[tid] * (1.0f / NN);
        float v2 = stat2[128 + tid] * (1.0f / NN) - m2 * m2;
        float s2 = g2[tid] * rsqrtf(v2 + EPSV);
        sc2[tid] = s2; bi2[tid] = b2[tid] - m2 * s2;
        float m4 = stat4[tid] * (1.0f / NN);
        float v4 = stat4[128 + tid] * (1.0f / NN) - m4 * m4;
        float s4 = g4[tid] * rsqrtf(v4 + EPSV);
        sc4[tid] = s4; bi4[tid] = b4[tid] - m4 * s4;
    }
    for (int i = tid; i < 1024; i += 256) wT[i] = w_out[(i & 7) * 128 + (i >> 3)];
    if (tid < 8) bo[tid] = b_out[tid];
    __syncthreads();

    const int l = tid & 63, wv = tid >> 6;
    const int sub = l & 7, rl = l >> 3;
    const int row = blockIdx.x * 32 + wv * 8 + rl;   // grid sized so row < NN always

    const ushort8v* p2 = (const ushort8v*)(y2 + (size_t)row * 128 + sub * 16);
    const ushort8v* p4 = (const ushort8v*)(y4 + (size_t)row * 128 + sub * 16);

    float p[8];
#pragma unroll
    for (int o = 0; o < 8; ++o) p[o] = 0.f;

#pragma unroll
    for (int jj = 0; jj < 2; ++jj) {
        ushort8v a2 = p2[jj];
        ushort8v a4 = p4[jj];
#pragma unroll
        for (int e = 0; e < 8; ++e) {
            int c = sub * 16 + jj * 8 + e;
            float i2 = fmaxf(b2f(a2[e]) * sc2[c] + bi2[c], 0.f);
            float x4 = b2f(a4[e]) * sc4[c] + bi4[c];
            float x5 = fmaxf(x4 + i2, 0.f);
            const f32x4* wp = (const f32x4*)(wT + c * 8);
            f32x4 wa = wp[0], wb = wp[1];
            p[0] += x5 * wa[0]; p[1] += x5 * wa[1]; p[2] += x5 * wa[2]; p[3] += x5 * wa[3];
            p[4] += x5 * wb[0]; p[5] += x5 * wb[1]; p[6] += x5 * wb[2]; p[7] += x5 * wb[3];
        }
    }
#pragma unroll
    for (int o = 0; o < 8; ++o) {
        p[o] += __shfl_xor(p[o], 1);
        p[o] += __shfl_xor(p[o], 2);
        p[o] += __shfl_xor(p[o], 4);
    }
    out[(size_t)row * 8 + sub] = p[sub] + bo[sub];
}

// ---------------------------------------------------------------------------
extern "C" void kernel_launch(void* const* d_in, const int* in_sizes, int n_in,
                              void* d_out, int out_size, void* d_ws, size_t ws_size,
                              hipStream_t stream)
{
    const float* feat  = (const float*)d_in[0];
    // d_in[1] coord, d_in[2] knn_idx, d_in[3] offset: dead code in reference
    const float* w1    = (const float*)d_in[4];
    const float* g1    = (const float*)d_in[5];
    const float* b1    = (const float*)d_in[6];
    const float* w2    = (const float*)d_in[7];
    const float* g2    = (const float*)d_in[8];
    const float* b2    = (const float*)d_in[9];
    const float* w3    = (const float*)d_in[10];
    const float* g3    = (const float*)d_in[11];
    const float* b3    = (const float*)d_in[12];
    const float* w4    = (const float*)d_in[13];
    const float* g4    = (const float*)d_in[14];
    const float* b4    = (const float*)d_in[15];
    const float* w_out = (const float*)d_in[16];
    const float* b_out = (const float*)d_in[17];

    char* ws = (char*)d_ws;
    const size_t sz128 = (size_t)NP * 128 * 2;   // bf16 N x 128
    const size_t sz256 = (size_t)NP * 256 * 2;   // bf16 N x 256
    unsigned short* y1 = (unsigned short*)(ws);
    unsigned short* y2 = (unsigned short*)(ws + sz128);
    unsigned short* y3 = (unsigned short*)(ws + 2 * sz128);
    unsigned short* y4 = (unsigned short*)(ws + 2 * sz128 + sz256);
    float* stats       = (float*)(ws + 3 * sz128 + sz256);
    float* stat1 = stats;          // 2*128
    float* stat2 = stats + 256;    // 2*128
    float* stat3 = stats + 512;    // 2*256
    float* stat4 = stats + 1024;   // 2*128
    unsigned short* wb = (unsigned short*)(stats + 1280);  // 81920 bf16 frag weights

    hipMemsetAsync(stats, 0, 1280 * sizeof(float), stream);

    wprep_kernel<<<dim3(320), 256, 0, stream>>>(w2, w3, w4, wb);
    k1_kernel<<<dim3(938), 256, 0, stream>>>(feat, w1, y1, stat1);
    gemm_bn_kernel<128><<<dim3(938, 1), 256, 0, stream>>>(y1, stat1, g1, b1, wb,         y2, stat2, 128);
    gemm_bn_kernel<128><<<dim3(938, 2), 256, 0, stream>>>(y2, stat2, g2, b2, wb + 16384, y3, stat3, 256);
    gemm_bn_kernel<256><<<dim3(938, 1), 256, 0, stream>>>(y3, stat3, g3, b3, wb + 49152, y4, stat4, 128);
    k5_kernel<<<dim3(3750), 256, 0, stream>>>(y2, y4, stat2, g2, b2, stat4, g4, b4,
                                              w_out, b_out, (float*)d_out);
}

// Round 3
// 210.408 us; speedup vs baseline: 1.4816x; 1.4816x over previous
//
#include <hip/hip_runtime.h>

#define NN   120000
#define NP   120064   // 938 * 128, padded rows
#define EPSV 1e-5f
#define NSLICE 8

typedef __attribute__((ext_vector_type(8))) short          short8v;   // bf16 MFMA frag
typedef __attribute__((ext_vector_type(8))) unsigned short ushort8v;
typedef __attribute__((ext_vector_type(4))) float          f32x4;

__device__ __forceinline__ float b2f(unsigned short u) {
    union { unsigned int i; float f; } x; x.i = ((unsigned int)u) << 16; return x.f;
}
__device__ __forceinline__ unsigned short f2b(float f) {
    union { float f; unsigned int i; } x; x.f = f;
    unsigned int i = x.i + 0x7FFFu + ((x.i >> 16) & 1u);
    return (unsigned short)(i >> 16);
}

// raw barrier: lgkm drain only — prefetch global loads stay in flight (no vmcnt0)
#define BARRIER() do {                                        \
    asm volatile("s_waitcnt lgkmcnt(0)" ::: "memory");        \
    __builtin_amdgcn_s_barrier();                             \
    asm volatile("" ::: "memory");                            \
} while (0)

// ---------------------------------------------------------------------------
// wprep: w2/w3/w4 (f32 [cout][kd]) -> bf16 MFMA-fragment-linear layout.
// ---------------------------------------------------------------------------
__global__ __launch_bounds__(256) void wprep_kernel(
    const float* __restrict__ w2, const float* __restrict__ w3,
    const float* __restrict__ w4, unsigned short* __restrict__ wb)
{
    int t = blockIdx.x * 256 + threadIdx.x;
    const float* src; int KD, ks; unsigned short* dst; int f;
    if (t < 16384)      { src = w2; KD = 128; ks = 2; dst = wb;         f = t; }
    else if (t < 49152) { src = w3; KD = 128; ks = 2; dst = wb + 16384; f = t - 16384; }
    else                { src = w4; KD = 256; ks = 3; dst = wb + 49152; f = t - 49152; }
    int e = f & 7, l = (f >> 3) & 63;
    int rest = f >> 9;
    int kb = rest & ((1 << ks) - 1);
    int cb = rest >> ks;
    int col = cb * 16 + (l & 15);
    int k = kb * 32 + (l >> 4) * 8 + e;
    dst[f] = f2b(src[col * KD + k]);
}

// ---------------------------------------------------------------------------
// K1: y1 = feat @ w1.T (K=5), raw output, sliced per-channel stats.
// 235 blocks x 512 rows.
// ---------------------------------------------------------------------------
__global__ __launch_bounds__(256) void k1_kernel(
    const float* __restrict__ feat, const float* __restrict__ w1,
    unsigned short* __restrict__ y1, float* __restrict__ stat1)
{
    __shared__ float red[512];
    const int tid = threadIdx.x;
    const int c = tid & 127;
    const int rh = tid >> 7;
    const int rowbase = blockIdx.x * 512;

    float wr_[5];
#pragma unroll
    for (int k = 0; k < 5; ++k) wr_[k] = w1[c * 5 + k];

    float ls = 0.f, lq = 0.f;
#pragma unroll 8
    for (int i = 0; i < 256; ++i) {
        int row = rowbase + i * 2 + rh;
        if (row < NP) {
            float y = 0.f;
            if (row < NN) {
                const float* fp = feat + (size_t)row * 5;
                y = fp[0]*wr_[0] + fp[1]*wr_[1] + fp[2]*wr_[2] + fp[3]*wr_[3] + fp[4]*wr_[4];
            }
            y1[(size_t)row * 128 + c] = f2b(y);
            ls += y; lq += y * y;
        }
    }
    red[tid] = ls; red[tid + 256] = lq;
    __syncthreads();
    if (tid < 128) {
        float* dst = stat1 + (blockIdx.x & (NSLICE - 1)) * 256;
        atomicAdd(dst + tid,       red[tid]       + red[tid + 128]);
        atomicAdd(dst + 128 + tid, red[tid + 256] + red[tid + 384]);
    }
}

// ---------------------------------------------------------------------------
// Pipelined GEMM: TILES row-tiles/block, 2-phase reg-staged prefetch,
// fused input-BN+relu, block-reduced sliced output stats.
// ---------------------------------------------------------------------------
template<int KD, int TILES>
__global__ __launch_bounds__(256, 2) void gemm_bn_kernel(
    const unsigned short* __restrict__ X, const float* __restrict__ statsIn,
    const float* __restrict__ gIn, const float* __restrict__ bIn,
    const unsigned short* __restrict__ Wf, unsigned short* __restrict__ Y,
    float* __restrict__ statsOut, int coutTotal)
{
    constexpr int KCH  = KD / 128;       // K-chunks per tile
    constexpr int NCH  = TILES * KCH;    // total chunks streamed
    constexpr int KBLK = KD / 32;
    __shared__ char  As[2][32768];
    __shared__ float scl[KD], bia[KD];
    __shared__ float red[512];

    const int tid = threadIdx.x;
    const int l = tid & 63, wv = tid >> 6;
    const int wr = wv >> 1, wc = wv & 1;
    const int lm = l & 15, lg = l >> 4;
    const int row0 = blockIdx.x * (128 * TILES);
    const int cbase = blockIdx.y * 128;
    const int cb0 = (cbase >> 4) + wc * 4;

    ushort8v xb[2][8];
    short8v  bfr[16];   // resident B frags (KCH==1 layers)

    auto xload = [&](int cc, int buf) {
        const unsigned short* base = X + (size_t)(row0 + (cc / KCH) * 128) * KD + (cc % KCH) * 128;
#pragma unroll
        for (int i = 0; i < 8; ++i) {
            int e = i * 256 + tid;
            xb[buf][i] = *(const ushort8v*)(base + (size_t)(e >> 4) * KD + (e & 15) * 8);
        }
    };
    auto bnwrite = [&](int buf, int koff) {
        char* dst = As[buf];
#pragma unroll
        for (int i = 0; i < 8; ++i) {
            int e = i * 256 + tid;
            int r = e >> 4;
            int k8 = (e & 15) * 8;
            ushort8v v = xb[buf][i];
            f32x4 s0 = *(const f32x4*)(scl + koff + k8);
            f32x4 s1 = *(const f32x4*)(scl + koff + k8 + 4);
            f32x4 c0 = *(const f32x4*)(bia + koff + k8);
            f32x4 c1 = *(const f32x4*)(bia + koff + k8 + 4);
            ushort8v o;
#pragma unroll
            for (int j = 0; j < 4; ++j)
                o[j] = f2b(fmaxf(b2f(v[j]) * s0[j] + c0[j], 0.f));
#pragma unroll
            for (int j = 0; j < 4; ++j)
                o[4 + j] = f2b(fmaxf(b2f(v[4 + j]) * s1[j] + c1[j], 0.f));
            *(ushort8v*)(dst + r * 256 + ((k8 * 2) ^ ((r & 7) << 4))) = o;
        }
    };

    // ---- prologue: issue prefetches, BN params, stage chunk 0 ----
    xload(0, 0);
    xload(1, 1);
    if (KCH == 1) {
#pragma unroll
        for (int kk = 0; kk < 4; ++kk)
#pragma unroll
            for (int ni = 0; ni < 4; ++ni)
                bfr[kk * 4 + ni] = *(const short8v*)(Wf + ((size_t)((cb0 + ni) * KBLK + kk) * 64 + l) * 8);
    }
    if (tid < KD) {
        float s = 0.f, q = 0.f;
#pragma unroll
        for (int j = 0; j < NSLICE; ++j) {
            s += statsIn[j * 2 * KD + tid];
            q += statsIn[j * 2 * KD + KD + tid];
        }
        float mean = s * (1.0f / NN);
        float var  = q * (1.0f / NN) - mean * mean;
        float sc   = gIn[tid] * rsqrtf(var + EPSV);
        scl[tid] = sc;
        bia[tid] = bIn[tid] - mean * sc;
    }
    __syncthreads();          // scl/bia visible (prologue only; drains prefetch once)
    bnwrite(0, 0);
    BARRIER();

    f32x4 acc[4][4] = {};
    float ss[4] = {}, qq[4] = {};

#pragma unroll
    for (int c = 0; c < NCH; ++c) {
        const int kc = c % KCH;
        const int tb = row0 + (c / KCH) * 128;
        char* Ac = As[c & 1];

        if (c + 2 < NCH) xload(c + 2, c & 1);   // issue-early; stays in flight across raw barriers

        short8v bl[16];
        if (KCH == 2) {
#pragma unroll
            for (int kk = 0; kk < 4; ++kk)
#pragma unroll
                for (int ni = 0; ni < 4; ++ni)
                    bl[kk * 4 + ni] = *(const short8v*)(Wf + ((size_t)((cb0 + ni) * KBLK + kc * 4 + kk) * 64 + l) * 8);
        }

        // ---- MFMA over this chunk ----
#pragma unroll
        for (int kk = 0; kk < 4; ++kk) {
            short8v a[4];
            const int kb2 = (kk * 32 + lg * 8) * 2;
#pragma unroll
            for (int mi = 0; mi < 4; ++mi) {
                int r = wr * 64 + mi * 16 + lm;
                a[mi] = *(const short8v*)(Ac + r * 256 + (kb2 ^ ((r & 7) << 4)));
            }
#pragma unroll
            for (int mi = 0; mi < 4; ++mi)
#pragma unroll
                for (int ni = 0; ni < 4; ++ni)
                    acc[mi][ni] = __builtin_amdgcn_mfma_f32_16x16x32_bf16(
                        a[mi], (KCH == 2) ? bl[kk * 4 + ni] : bfr[kk * 4 + ni], acc[mi][ni], 0, 0, 0);
        }

        if (kc == KCH - 1) {
            // ---- stats accumulate in regs (masked rows) ----
#pragma unroll
            for (int ni = 0; ni < 4; ++ni)
#pragma unroll
                for (int mi = 0; mi < 4; ++mi)
#pragma unroll
                    for (int r = 0; r < 4; ++r) {
                        int rowg = tb + wr * 64 + mi * 16 + lg * 4 + r;
                        float v = (rowg < NN) ? acc[mi][ni][r] : 0.f;
                        ss[ni] += v; qq[ni] += v * v;
                    }
            // ---- C -> LDS (reuse Ac) -> coalesced global store ----
            BARRIER();
#pragma unroll
            for (int mi = 0; mi < 4; ++mi)
#pragma unroll
                for (int ni = 0; ni < 4; ++ni)
#pragma unroll
                    for (int r = 0; r < 4; ++r) {
                        int rw = wr * 64 + mi * 16 + lg * 4 + r;
                        int colb = (wc * 64 + ni * 16 + lm) * 2;
                        *(unsigned short*)(Ac + rw * 256 + (colb ^ ((rw & 7) << 4))) = f2b(acc[mi][ni][r]);
                    }
            BARRIER();
            {
                int rw = tid >> 1;
                int hb = (tid & 1) * 128;
                unsigned short* Yrow = Y + (size_t)(tb + rw) * coutTotal + cbase + (hb >> 1);
#pragma unroll
                for (int j = 0; j < 8; ++j)
                    *(ushort8v*)(Yrow + j * 8) =
                        *(const ushort8v*)(Ac + rw * 256 + ((hb + j * 16) ^ ((rw & 7) << 4)));
            }
#pragma unroll
            for (int mi = 0; mi < 4; ++mi)
#pragma unroll
                for (int ni = 0; ni < 4; ++ni)
                    acc[mi][ni] = f32x4{0.f, 0.f, 0.f, 0.f};
        }

        if (c + 1 < NCH) {
            bnwrite((c + 1) & 1, ((c + 1) % KCH) * 128);
            BARRIER();
        }
    }

    // ---- block-level stats reduce -> one atomic per channel per block ----
#pragma unroll
    for (int ni = 0; ni < 4; ++ni) {
        ss[ni] += __shfl_xor(ss[ni], 16); ss[ni] += __shfl_xor(ss[ni], 32);
        qq[ni] += __shfl_xor(qq[ni], 16); qq[ni] += __shfl_xor(qq[ni], 32);
    }
    if (lg == 0) {
#pragma unroll
        for (int ni = 0; ni < 4; ++ni) {
            red[(wv * 4 + ni) * 16 + lm]       = ss[ni];
            red[256 + (wv * 4 + ni) * 16 + lm] = qq[ni];
        }
    }
    __syncthreads();
    {
        int ch = tid & 127, which = tid >> 7;
        int wcv = (ch >> 6) & 1, niv = (ch >> 4) & 3, lmv = ch & 15;
        float v = red[which * 256 + ((0 * 2 + wcv) * 4 + niv) * 16 + lmv]
                + red[which * 256 + ((1 * 2 + wcv) * 4 + niv) * 16 + lmv];
        atomicAdd(statsOut + ((size_t)(blockIdx.x & (NSLICE - 1)) * 2 + which) * coutTotal + cbase + ch, v);
    }
}

// ---------------------------------------------------------------------------
// K5: x5 = relu( BN4(y4) + relu(BN2(y2)) ); logits = x5 @ w_out.T + b_out
// ---------------------------------------------------------------------------
__global__ __launch_bounds__(256) void k5_kernel(
    const unsigned short* __restrict__ y2, const unsigned short* __restrict__ y4,
    const float* __restrict__ stat2, const float* __restrict__ g2, const float* __restrict__ b2,
    const float* __restrict__ stat4, const float* __restrict__ g4, const float* __restrict__ b4,
    const float* __restrict__ w_out, const float* __restrict__ b_out,
    float* __restrict__ out)
{
    __shared__ float wT[128 * 8];
    __shared__ float sc2[128], bi2[128], sc4[128], bi4[128], bo[8];
    const int tid = threadIdx.x;

    if (tid < 128) {
        float s2 = 0.f, q2 = 0.f, s4 = 0.f, q4 = 0.f;
#pragma unroll
        for (int j = 0; j < NSLICE; ++j) {
            s2 += stat2[j * 256 + tid];       q2 += stat2[j * 256 + 128 + tid];
            s4 += stat4[j * 256 + tid];       q4 += stat4[j * 256 + 128 + tid];
        }
        float m2 = s2 * (1.0f / NN);
        float v2 = q2 * (1.0f / NN) - m2 * m2;
        float t2 = g2[tid] * rsqrtf(v2 + EPSV);
        sc2[tid] = t2; bi2[tid] = b2[tid] - m2 * t2;
        float m4 = s4 * (1.0f / NN);
        float v4 = q4 * (1.0f / NN) - m4 * m4;
        float t4 = g4[tid] * rsqrtf(v4 + EPSV);
        sc4[tid] = t4; bi4[tid] = b4[tid] - m4 * t4;
    }
    for (int i = tid; i < 1024; i += 256) wT[i] = w_out[(i & 7) * 128 + (i >> 3)];
    if (tid < 8) bo[tid] = b_out[tid];
    __syncthreads();

    const int l = tid & 63, wv = tid >> 6;
    const int sub = l & 7, rl = l >> 3;
    const int row = blockIdx.x * 32 + wv * 8 + rl;   // 3750*32 = 120000, always < NN

    const ushort8v* p2 = (const ushort8v*)(y2 + (size_t)row * 128 + sub * 16);
    const ushort8v* p4 = (const ushort8v*)(y4 + (size_t)row * 128 + sub * 16);

    float p[8];
#pragma unroll
    for (int o = 0; o < 8; ++o) p[o] = 0.f;

#pragma unroll
    for (int jj = 0; jj < 2; ++jj) {
        ushort8v a2 = p2[jj];
        ushort8v a4 = p4[jj];
#pragma unroll
        for (int e = 0; e < 8; ++e) {
            int c = sub * 16 + jj * 8 + e;
            float i2 = fmaxf(b2f(a2[e]) * sc2[c] + bi2[c], 0.f);
            float x4 = b2f(a4[e]) * sc4[c] + bi4[c];
            float x5 = fmaxf(x4 + i2, 0.f);
            const f32x4* wp = (const f32x4*)(wT + c * 8);
            f32x4 wa = wp[0], wb = wp[1];
            p[0] += x5 * wa[0]; p[1] += x5 * wa[1]; p[2] += x5 * wa[2]; p[3] += x5 * wa[3];
            p[4] += x5 * wb[0]; p[5] += x5 * wb[1]; p[6] += x5 * wb[2]; p[7] += x5 * wb[3];
        }
    }
#pragma unroll
    for (int o = 0; o < 8; ++o) {
        p[o] += __shfl_xor(p[o], 1);
        p[o] += __shfl_xor(p[o], 2);
        p[o] += __shfl_xor(p[o], 4);
    }
    out[(size_t)row * 8 + sub] = p[sub] + bo[sub];
}

// ---------------------------------------------------------------------------
extern "C" void kernel_launch(void* const* d_in, const int* in_sizes, int n_in,
                              void* d_out, int out_size, void* d_ws, size_t ws_size,
                              hipStream_t stream)
{
    const float* feat  = (const float*)d_in[0];
    // d_in[1] coord, d_in[2] knn_idx, d_in[3] offset: dead code in reference
    const float* w1    = (const float*)d_in[4];
    const float* g1    = (const float*)d_in[5];
    const float* b1    = (const float*)d_in[6];
    const float* w2    = (const float*)d_in[7];
    const float* g2    = (const float*)d_in[8];
    const float* b2    = (const float*)d_in[9];
    const float* w3    = (const float*)d_in[10];
    const float* g3    = (const float*)d_in[11];
    const float* b3    = (const float*)d_in[12];
    const float* w4    = (const float*)d_in[13];
    const float* g4    = (const float*)d_in[14];
    const float* b4    = (const float*)d_in[15];
    const float* w_out = (const float*)d_in[16];
    const float* b_out = (const float*)d_in[17];

    char* ws = (char*)d_ws;
    const size_t sz128 = (size_t)NP * 128 * 2;   // bf16 N x 128
    const size_t sz256 = (size_t)NP * 256 * 2;   // bf16 N x 256
    unsigned short* y1 = (unsigned short*)(ws);
    unsigned short* y2 = (unsigned short*)(ws + sz128);
    unsigned short* y3 = (unsigned short*)(ws + 2 * sz128);
    unsigned short* y4 = (unsigned short*)(ws + 2 * sz128 + sz256);
    float* stats       = (float*)(ws + 3 * sz128 + sz256);
    // sliced stats: [8][2][C]
    float* stat1 = stats;           // 8*2*128 = 2048
    float* stat2 = stats + 2048;    // 2048
    float* stat3 = stats + 4096;    // 8*2*256 = 4096
    float* stat4 = stats + 8192;    // 2048
    unsigned short* wb = (unsigned short*)(stats + 10240);  // 81920 bf16 frag weights

    hipMemsetAsync(stats, 0, 10240 * sizeof(float), stream);

    wprep_kernel<<<dim3(320), 256, 0, stream>>>(w2, w3, w4, wb);
    k1_kernel<<<dim3(235), 256, 0, stream>>>(feat, w1, y1, stat1);
    gemm_bn_kernel<128, 2><<<dim3(469, 1), 256, 0, stream>>>(y1, stat1, g1, b1, wb,         y2, stat2, 128);
    gemm_bn_kernel<128, 2><<<dim3(469, 2), 256, 0, stream>>>(y2, stat2, g2, b2, wb + 16384, y3, stat3, 256);
    gemm_bn_kernel<256, 2><<<dim3(469, 1), 256, 0, stream>>>(y3, stat3, g3, b3, wb + 49152, y4, stat4, 128);
    k5_kernel<<<dim3(3750), 256, 0, stream>>>(y2, y4, stat2, g2, b2, stat4, g4, b4,
                                              w_out, b_out, (float*)d_out);
}

// Round 4
// 156.724 us; speedup vs baseline: 1.9891x; 1.3425x over previous
//
#include <hip/hip_runtime.h>

#define NN   120000
#define NP   120064   // 938 * 128, padded rows
#define EPSV 1e-5f
#define NSLICE 8

typedef __attribute__((ext_vector_type(8))) short          short8v;   // bf16 MFMA frag
typedef __attribute__((ext_vector_type(8))) unsigned short ushort8v;
typedef __attribute__((ext_vector_type(4))) float          f32x4;

__device__ __forceinline__ float b2f(unsigned short u) {
    union { unsigned int i; float f; } x; x.i = ((unsigned int)u) << 16; return x.f;
}
__device__ __forceinline__ unsigned short f2b(float f) {
    union { float f; unsigned int i; } x; x.f = f;
    unsigned int i = x.i + 0x7FFFu + ((x.i >> 16) & 1u);
    return (unsigned short)(i >> 16);
}

// raw barrier: lgkm drain only — prefetch global loads stay in flight (no vmcnt0)
#define BARRIER() do {                                        \
    asm volatile("s_waitcnt lgkmcnt(0)" ::: "memory");        \
    __builtin_amdgcn_s_barrier();                             \
    asm volatile("" ::: "memory");                            \
} while (0)

// ---------------------------------------------------------------------------
// wprep: w2/w3/w4 (f32 [cout][kd]) -> bf16 MFMA-fragment-linear layout.
// ---------------------------------------------------------------------------
__global__ __launch_bounds__(256) void wprep_kernel(
    const float* __restrict__ w2, const float* __restrict__ w3,
    const float* __restrict__ w4, unsigned short* __restrict__ wb)
{
    int t = blockIdx.x * 256 + threadIdx.x;
    const float* src; int KD, ks; unsigned short* dst; int f;
    if (t < 16384)      { src = w2; KD = 128; ks = 2; dst = wb;         f = t; }
    else if (t < 49152) { src = w3; KD = 128; ks = 2; dst = wb + 16384; f = t - 16384; }
    else                { src = w4; KD = 256; ks = 3; dst = wb + 49152; f = t - 49152; }
    int e = f & 7, l = (f >> 3) & 63;
    int rest = f >> 9;
    int kb = rest & ((1 << ks) - 1);
    int cb = rest >> ks;
    int col = cb * 16 + (l & 15);
    int k = kb * 32 + (l >> 4) * 8 + e;
    dst[f] = f2b(src[col * KD + k]);
}

// ---------------------------------------------------------------------------
// K1: y1 = feat @ w1.T (K=5), raw bf16 output, sliced per-channel stats.
// 938 blocks x 128 rows. Lane g=tid&15 owns 8 channels -> 16B stores;
// a wave writes 1KB contiguous (4 rows x 256B).
// ---------------------------------------------------------------------------
__global__ __launch_bounds__(256) void k1_kernel(
    const float* __restrict__ feat, const float* __restrict__ w1,
    unsigned short* __restrict__ y1, float* __restrict__ stat1)
{
    __shared__ float red[1024];
    const int tid = threadIdx.x;
    const int g = tid & 15;          // channel group (8 channels)
    const int rsub = tid >> 4;       // row within pass (0..15)
    const int rowbase = blockIdx.x * 128;

    float wr_[8][5];
#pragma unroll
    for (int j = 0; j < 8; ++j)
#pragma unroll
        for (int k = 0; k < 5; ++k)
            wr_[j][k] = w1[(g * 8 + j) * 5 + k];

    float ss[8] = {}, qq[8] = {};
#pragma unroll
    for (int p = 0; p < 8; ++p) {
        int row = rowbase + p * 16 + rsub;
        float f0 = 0.f, f1 = 0.f, f2 = 0.f, f3 = 0.f, f4 = 0.f;
        if (row < NN) {
            const float* fp = feat + (size_t)row * 5;
            f0 = fp[0]; f1 = fp[1]; f2 = fp[2]; f3 = fp[3]; f4 = fp[4];
        }
        ushort8v o;
#pragma unroll
        for (int j = 0; j < 8; ++j) {
            float y = f0*wr_[j][0] + f1*wr_[j][1] + f2*wr_[j][2] + f3*wr_[j][3] + f4*wr_[j][4];
            o[j] = f2b(y);
            ss[j] += y; qq[j] += y * y;
        }
        *(ushort8v*)(y1 + (size_t)row * 128 + g * 8) = o;   // row < NP always
    }
#pragma unroll
    for (int j = 0; j < 8; ++j) {
        ss[j] += __shfl_xor(ss[j], 16); ss[j] += __shfl_xor(ss[j], 32);
        qq[j] += __shfl_xor(qq[j], 16); qq[j] += __shfl_xor(qq[j], 32);
    }
    const int w = tid >> 6, l = tid & 63;
    if ((l >> 4) == 0) {
#pragma unroll
        for (int j = 0; j < 8; ++j) {
            red[w * 128 + g * 8 + j]       = ss[j];
            red[512 + w * 128 + g * 8 + j] = qq[j];
        }
    }
    __syncthreads();
    if (tid < 128) {
        float s = red[tid] + red[128 + tid] + red[256 + tid] + red[384 + tid];
        float q = red[512 + tid] + red[640 + tid] + red[768 + tid] + red[896 + tid];
        float* dst = stat1 + (blockIdx.x & (NSLICE - 1)) * 256;
        atomicAdd(dst + tid,       s);
        atomicAdd(dst + 128 + tid, q);
    }
}

// ---------------------------------------------------------------------------
// Pipelined GEMM: TILES row-tiles/block, 2-phase reg-staged prefetch,
// fused input-BN+relu, block-reduced sliced output stats.
// ---------------------------------------------------------------------------
template<int KD, int TILES>
__global__ __launch_bounds__(256, 2) void gemm_bn_kernel(
    const unsigned short* __restrict__ X, const float* __restrict__ statsIn,
    const float* __restrict__ gIn, const float* __restrict__ bIn,
    const unsigned short* __restrict__ Wf, unsigned short* __restrict__ Y,
    float* __restrict__ statsOut, int coutTotal)
{
    constexpr int KCH  = KD / 128;       // K-chunks per tile
    constexpr int NCH  = TILES * KCH;    // total chunks streamed
    constexpr int KBLK = KD / 32;
    __shared__ char  As[2][32768];
    __shared__ float scl[KD], bia[KD];
    __shared__ float red[512];

    const int tid = threadIdx.x;
    const int l = tid & 63, wv = tid >> 6;
    const int wr = wv >> 1, wc = wv & 1;
    const int lm = l & 15, lg = l >> 4;
    const int row0 = blockIdx.x * (128 * TILES);
    const int cbase = blockIdx.y * 128;
    const int cb0 = (cbase >> 4) + wc * 4;

    ushort8v xb[2][8];
    short8v  bfr[16];   // resident B frags (KCH==1 layers)

    auto xload = [&](int cc, int buf) {
        const unsigned short* base = X + (size_t)(row0 + (cc / KCH) * 128) * KD + (cc % KCH) * 128;
#pragma unroll
        for (int i = 0; i < 8; ++i) {
            int e = i * 256 + tid;
            xb[buf][i] = *(const ushort8v*)(base + (size_t)(e >> 4) * KD + (e & 15) * 8);
        }
    };
    auto bnwrite = [&](int buf, int koff) {
        char* dst = As[buf];
#pragma unroll
        for (int i = 0; i < 8; ++i) {
            int e = i * 256 + tid;
            int r = e >> 4;
            int k8 = (e & 15) * 8;
            ushort8v v = xb[buf][i];
            f32x4 s0 = *(const f32x4*)(scl + koff + k8);
            f32x4 s1 = *(const f32x4*)(scl + koff + k8 + 4);
            f32x4 c0 = *(const f32x4*)(bia + koff + k8);
            f32x4 c1 = *(const f32x4*)(bia + koff + k8 + 4);
            ushort8v o;
#pragma unroll
            for (int j = 0; j < 4; ++j)
                o[j] = f2b(fmaxf(b2f(v[j]) * s0[j] + c0[j], 0.f));
#pragma unroll
            for (int j = 0; j < 4; ++j)
                o[4 + j] = f2b(fmaxf(b2f(v[4 + j]) * s1[j] + c1[j], 0.f));
            *(ushort8v*)(dst + r * 256 + ((k8 * 2) ^ ((r & 7) << 4))) = o;
        }
    };

    // ---- prologue: issue prefetches, BN params, stage chunk 0 ----
    xload(0, 0);
    xload(1, 1);
    if (KCH == 1) {
#pragma unroll
        for (int kk = 0; kk < 4; ++kk)
#pragma unroll
            for (int ni = 0; ni < 4; ++ni)
                bfr[kk * 4 + ni] = *(const short8v*)(Wf + ((size_t)((cb0 + ni) * KBLK + kk) * 64 + l) * 8);
    }
    if (tid < KD) {
        float s = 0.f, q = 0.f;
#pragma unroll
        for (int j = 0; j < NSLICE; ++j) {
            s += statsIn[j * 2 * KD + tid];
            q += statsIn[j * 2 * KD + KD + tid];
        }
        float mean = s * (1.0f / NN);
        float var  = q * (1.0f / NN) - mean * mean;
        float sc   = gIn[tid] * rsqrtf(var + EPSV);
        scl[tid] = sc;
        bia[tid] = bIn[tid] - mean * sc;
    }
    __syncthreads();          // scl/bia visible (prologue only; drains prefetch once)
    bnwrite(0, 0);
    BARRIER();

    f32x4 acc[4][4] = {};
    float ss[4] = {}, qq[4] = {};

#pragma unroll
    for (int c = 0; c < NCH; ++c) {
        const int kc = c % KCH;
        const int tb = row0 + (c / KCH) * 128;
        char* Ac = As[c & 1];

        if (c + 2 < NCH) xload(c + 2, c & 1);   // issue-early; stays in flight across raw barriers

        short8v bl[16];
        if (KCH == 2) {
#pragma unroll
            for (int kk = 0; kk < 4; ++kk)
#pragma unroll
                for (int ni = 0; ni < 4; ++ni)
                    bl[kk * 4 + ni] = *(const short8v*)(Wf + ((size_t)((cb0 + ni) * KBLK + kc * 4 + kk) * 64 + l) * 8);
        }

        // ---- MFMA over this chunk ----
#pragma unroll
        for (int kk = 0; kk < 4; ++kk) {
            short8v a[4];
            const int kb2 = (kk * 32 + lg * 8) * 2;
#pragma unroll
            for (int mi = 0; mi < 4; ++mi) {
                int r = wr * 64 + mi * 16 + lm;
                a[mi] = *(const short8v*)(Ac + r * 256 + (kb2 ^ ((r & 7) << 4)));
            }
#pragma unroll
            for (int mi = 0; mi < 4; ++mi)
#pragma unroll
                for (int ni = 0; ni < 4; ++ni)
                    acc[mi][ni] = __builtin_amdgcn_mfma_f32_16x16x32_bf16(
                        a[mi], (KCH == 2) ? bl[kk * 4 + ni] : bfr[kk * 4 + ni], acc[mi][ni], 0, 0, 0);
        }

        if (kc == KCH - 1) {
            // ---- stats accumulate in regs (masked rows) ----
#pragma unroll
            for (int ni = 0; ni < 4; ++ni)
#pragma unroll
                for (int mi = 0; mi < 4; ++mi)
#pragma unroll
                    for (int r = 0; r < 4; ++r) {
                        int rowg = tb + wr * 64 + mi * 16 + lg * 4 + r;
                        float v = (rowg < NN) ? acc[mi][ni][r] : 0.f;
                        ss[ni] += v; qq[ni] += v * v;
                    }
            // ---- C -> LDS (reuse Ac) -> coalesced global store ----
            BARRIER();
#pragma unroll
            for (int mi = 0; mi < 4; ++mi)
#pragma unroll
                for (int ni = 0; ni < 4; ++ni)
#pragma unroll
                    for (int r = 0; r < 4; ++r) {
                        int rw = wr * 64 + mi * 16 + lg * 4 + r;
                        int colb = (wc * 64 + ni * 16 + lm) * 2;
                        *(unsigned short*)(Ac + rw * 256 + (colb ^ ((rw & 7) << 4))) = f2b(acc[mi][ni][r]);
                    }
            BARRIER();
            {
                int rw = tid >> 1;
                int hb = (tid & 1) * 128;
                unsigned short* Yrow = Y + (size_t)(tb + rw) * coutTotal + cbase + (hb >> 1);
#pragma unroll
                for (int j = 0; j < 8; ++j)
                    *(ushort8v*)(Yrow + j * 8) =
                        *(const ushort8v*)(Ac + rw * 256 + ((hb + j * 16) ^ ((rw & 7) << 4)));
            }
#pragma unroll
            for (int mi = 0; mi < 4; ++mi)
#pragma unroll
                for (int ni = 0; ni < 4; ++ni)
                    acc[mi][ni] = f32x4{0.f, 0.f, 0.f, 0.f};
        }

        if (c + 1 < NCH) {
            bnwrite((c + 1) & 1, ((c + 1) % KCH) * 128);
            BARRIER();
        }
    }

    // ---- block-level stats reduce -> one atomic per channel per block ----
#pragma unroll
    for (int ni = 0; ni < 4; ++ni) {
        ss[ni] += __shfl_xor(ss[ni], 16); ss[ni] += __shfl_xor(ss[ni], 32);
        qq[ni] += __shfl_xor(qq[ni], 16); qq[ni] += __shfl_xor(qq[ni], 32);
    }
    if (lg == 0) {
#pragma unroll
        for (int ni = 0; ni < 4; ++ni) {
            red[(wv * 4 + ni) * 16 + lm]       = ss[ni];
            red[256 + (wv * 4 + ni) * 16 + lm] = qq[ni];
        }
    }
    __syncthreads();
    {
        int ch = tid & 127, which = tid >> 7;
        int wcv = (ch >> 6) & 1, niv = (ch >> 4) & 3, lmv = ch & 15;
        float v = red[which * 256 + ((0 * 2 + wcv) * 4 + niv) * 16 + lmv]
                + red[which * 256 + ((1 * 2 + wcv) * 4 + niv) * 16 + lmv];
        atomicAdd(statsOut + ((size_t)(blockIdx.x & (NSLICE - 1)) * 2 + which) * coutTotal + cbase + ch, v);
    }
}

// ---------------------------------------------------------------------------
// K5: x5 = relu( BN4(y4) + relu(BN2(y2)) ); logits = x5 @ w_out.T + b_out
// ---------------------------------------------------------------------------
__global__ __launch_bounds__(256) void k5_kernel(
    const unsigned short* __restrict__ y2, const unsigned short* __restrict__ y4,
    const float* __restrict__ stat2, const float* __restrict__ g2, const float* __restrict__ b2,
    const float* __restrict__ stat4, const float* __restrict__ g4, const float* __restrict__ b4,
    const float* __restrict__ w_out, const float* __restrict__ b_out,
    float* __restrict__ out)
{
    __shared__ float wT[128 * 8];
    __shared__ float sc2[128], bi2[128], sc4[128], bi4[128], bo[8];
    const int tid = threadIdx.x;

    if (tid < 128) {
        float s2 = 0.f, q2 = 0.f, s4 = 0.f, q4 = 0.f;
#pragma unroll
        for (int j = 0; j < NSLICE; ++j) {
            s2 += stat2[j * 256 + tid];       q2 += stat2[j * 256 + 128 + tid];
            s4 += stat4[j * 256 + tid];       q4 += stat4[j * 256 + 128 + tid];
        }
        float m2 = s2 * (1.0f / NN);
        float v2 = q2 * (1.0f / NN) - m2 * m2;
        float t2 = g2[tid] * rsqrtf(v2 + EPSV);
        sc2[tid] = t2; bi2[tid] = b2[tid] - m2 * t2;
        float m4 = s4 * (1.0f / NN);
        float v4 = q4 * (1.0f / NN) - m4 * m4;
        float t4 = g4[tid] * rsqrtf(v4 + EPSV);
        sc4[tid] = t4; bi4[tid] = b4[tid] - m4 * t4;
    }
    for (int i = tid; i < 1024; i += 256) wT[i] = w_out[(i & 7) * 128 + (i >> 3)];
    if (tid < 8) bo[tid] = b_out[tid];
    __syncthreads();

    const int l = tid & 63, wv = tid >> 6;
    const int sub = l & 7, rl = l >> 3;
    const int row = blockIdx.x * 32 + wv * 8 + rl;   // 3750*32 = 120000, always < NN

    const ushort8v* p2 = (const ushort8v*)(y2 + (size_t)row * 128 + sub * 16);
    const ushort8v* p4 = (const ushort8v*)(y4 + (size_t)row * 128 + sub * 16);

    float p[8];
#pragma unroll
    for (int o = 0; o < 8; ++o) p[o] = 0.f;

#pragma unroll
    for (int jj = 0; jj < 2; ++jj) {
        ushort8v a2 = p2[jj];
        ushort8v a4 = p4[jj];
#pragma unroll
        for (int e = 0; e < 8; ++e) {
            int c = sub * 16 + jj * 8 + e;
            float i2 = fmaxf(b2f(a2[e]) * sc2[c] + bi2[c], 0.f);
            float x4 = b2f(a4[e]) * sc4[c] + bi4[c];
            float x5 = fmaxf(x4 + i2, 0.f);
            const f32x4* wp = (const f32x4*)(wT + c * 8);
            f32x4 wa = wp[0], wb = wp[1];
            p[0] += x5 * wa[0]; p[1] += x5 * wa[1]; p[2] += x5 * wa[2]; p[3] += x5 * wa[3];
            p[4] += x5 * wb[0]; p[5] += x5 * wb[1]; p[6] += x5 * wb[2]; p[7] += x5 * wb[3];
        }
    }
#pragma unroll
    for (int o = 0; o < 8; ++o) {
        p[o] += __shfl_xor(p[o], 1);
        p[o] += __shfl_xor(p[o], 2);
        p[o] += __shfl_xor(p[o], 4);
    }
    out[(size_t)row * 8 + sub] = p[sub] + bo[sub];
}

// ---------------------------------------------------------------------------
extern "C" void kernel_launch(void* const* d_in, const int* in_sizes, int n_in,
                              void* d_out, int out_size, void* d_ws, size_t ws_size,
                              hipStream_t stream)
{
    const float* feat  = (const float*)d_in[0];
    // d_in[1] coord, d_in[2] knn_idx, d_in[3] offset: dead code in reference
    const float* w1    = (const float*)d_in[4];
    const float* g1    = (const float*)d_in[5];
    const float* b1    = (const float*)d_in[6];
    const float* w2    = (const float*)d_in[7];
    const float* g2    = (const float*)d_in[8];
    const float* b2    = (const float*)d_in[9];
    const float* w3    = (const float*)d_in[10];
    const float* g3    = (const float*)d_in[11];
    const float* b3    = (const float*)d_in[12];
    const float* w4    = (const float*)d_in[13];
    const float* g4    = (const float*)d_in[14];
    const float* b4    = (const float*)d_in[15];
    const float* w_out = (const float*)d_in[16];
    const float* b_out = (const float*)d_in[17];

    char* ws = (char*)d_ws;
    const size_t sz128 = (size_t)NP * 128 * 2;   // bf16 N x 128
    const size_t sz256 = (size_t)NP * 256 * 2;   // bf16 N x 256
    unsigned short* y1 = (unsigned short*)(ws);
    unsigned short* y2 = (unsigned short*)(ws + sz128);
    unsigned short* y3 = (unsigned short*)(ws + 2 * sz128);
    unsigned short* y4 = (unsigned short*)(ws + 2 * sz128 + sz256);
    float* stats       = (float*)(ws + 3 * sz128 + sz256);
    // sliced stats: [8][2][C]
    float* stat1 = stats;           // 8*2*128 = 2048
    float* stat2 = stats + 2048;    // 2048
    float* stat3 = stats + 4096;    // 8*2*256 = 4096
    float* stat4 = stats + 8192;    // 2048
    unsigned short* wb = (unsigned short*)(stats + 10240);  // 81920 bf16 frag weights

    hipMemsetAsync(stats, 0, 10240 * sizeof(float), stream);

    wprep_kernel<<<dim3(320), 256, 0, stream>>>(w2, w3, w4, wb);
    k1_kernel<<<dim3(938), 256, 0, stream>>>(feat, w1, y1, stat1);
    gemm_bn_kernel<128, 2><<<dim3(469, 1), 256, 0, stream>>>(y1, stat1, g1, b1, wb,         y2, stat2, 128);
    gemm_bn_kernel<128, 2><<<dim3(469, 2), 256, 0, stream>>>(y2, stat2, g2, b2, wb + 16384, y3, stat3, 256);
    gemm_bn_kernel<256, 2><<<dim3(469, 1), 256, 0, stream>>>(y3, stat3, g3, b3, wb + 49152, y4, stat4, 128);
    k5_kernel<<<dim3(3750), 256, 0, stream>>>(y2, y4, stat2, g2, b2, stat4, g4, b4,
                                              w_out, b_out, (float*)d_out);
}